// Round 3
// baseline (185.981 us; speedup 1.0000x reference)
//
#include <hip/hip_runtime.h>

#define HW 1659      // 21*79
#define PADID 4096
#define EMB 20
#define HID 32
#define MAXLEN 64
#define PROJ_BLOCKS 128
#define SPB 4        // samples per block in bag kernel (reg-double-buffered)

typedef float v2f __attribute__((ext_vector_type(2)));

// DPP lane-permute helper (pure VALU, no LDS pipe). CTRL is an immediate.
template <int CTRL>
__device__ __forceinline__ float dppf(float v) {
    return __builtin_bit_cast(float,
        __builtin_amdgcn_update_dpp(0, __builtin_bit_cast(int, v),
                                    CTRL, 0xF, 0xF, true));
}
#define DPP_XOR1 0xB1   // quad_perm [1,0,3,2]
#define DPP_XOR2 0x4E   // quad_perm [2,3,0,1]
#define DPP_XOR7 0x141  // row_half_mirror (xor 7 within 16)
#define DPP_XORF 0x140  // row_mirror      (xor 15 within 16)

// LDS-only barrier: s_waitcnt lgkmcnt(0) + raw s_barrier. Unlike __syncthreads()
// this does NOT drain vmcnt, so prefetched global loads stay in flight across it.
// Valid here because all inter-thread traffic in the bag kernel is LDS.
__device__ __forceinline__ void bar_lds() {
    asm volatile("s_waitcnt lgkmcnt(0)" ::: "memory");
    __builtin_amdgcn_s_barrier();
}

// One sample's register-staged input (32 VGPRs payload + 2)
struct Samp {
    int4 c0, c1, c2, c3, k0, k1, k2, k3;
    int gp, gt;
};

// Issue all loads for sample b into S. sched_barrier(0) pins the issue point
// so the compiler cannot sink the loads toward their use (R1/R2 failure mode:
// VGPR=24 proved the loads were serialized into batches).
__device__ __forceinline__ void prefetch(Samp& S,
    const int* __restrict__ chars, const int* __restrict__ colors,
    int b, int tid)
{
    const int base = b * HW;
    const int pe = (4 - (base & 3)) & 3;       // peel to 16B alignment
    // nv = (HW - pe) >> 2 == 414 for all pe in 0..3
    const int nt = 3 - pe;                     // tail count (HW-pe-1656)
    const int4* c4 = (const int4*)(chars + base + pe);
    const int4* k4 = (const int4*)(colors + base + pe);

    S.c0 = c4[tid];       S.k0 = k4[tid];
    S.c1 = c4[tid + 128]; S.k1 = k4[tid + 128];
    S.c2 = c4[tid + 256]; S.k2 = k4[tid + 256];
    const int i3 = (tid < 30) ? tid + 384 : tid;   // 414 groups; dup slot0 if none
    S.c3 = c4[i3];        S.k3 = k4[i3];           // duplicate scatter is idempotent

    S.gp = -1; S.gt = -1;
    if (tid < pe) S.gp = (chars[base + tid] << 4) + colors[base + tid];
    if (tid < nt) {
        const int i = base + pe + 1656 + tid;
        S.gt = (chars[i] << 4) + colors[i];
    }
    __builtin_amdgcn_sched_barrier(0);
}

// Process one fully-staged sample: scatter -> scan/compact -> bag+emb outputs.
__device__ __forceinline__ void process(const Samp& S,
    unsigned char* pres, int* bagl, int* wsum,
    int b, int tid, int lane, int wv,
    const float* __restrict__ emb_table,
    float* __restrict__ out_emb, float* __restrict__ out_bag)
{
    bar_lds();                                   // prior iter's LDS readers done

    ((uint4*)pres)[tid]       = make_uint4(0u, 0u, 0u, 0u);
    ((uint4*)pres)[tid + 128] = make_uint4(0u, 0u, 0u, 0u);
    if (tid < 64) bagl[tid] = PADID;
    bar_lds();                                   // zero visible

    // scatter (compiler emits counted vmcnt here: waits for THIS sample's
    // loads while the next sample's prefetch stays outstanding)
    pres[(S.c0.x << 4) + S.k0.x] = 1;
    pres[(S.c0.y << 4) + S.k0.y] = 1;
    pres[(S.c0.z << 4) + S.k0.z] = 1;
    pres[(S.c0.w << 4) + S.k0.w] = 1;
    pres[(S.c1.x << 4) + S.k1.x] = 1;
    pres[(S.c1.y << 4) + S.k1.y] = 1;
    pres[(S.c1.z << 4) + S.k1.z] = 1;
    pres[(S.c1.w << 4) + S.k1.w] = 1;
    pres[(S.c2.x << 4) + S.k2.x] = 1;
    pres[(S.c2.y << 4) + S.k2.y] = 1;
    pres[(S.c2.z << 4) + S.k2.z] = 1;
    pres[(S.c2.w << 4) + S.k2.w] = 1;
    pres[(S.c3.x << 4) + S.k3.x] = 1;
    pres[(S.c3.y << 4) + S.k3.y] = 1;
    pres[(S.c3.z << 4) + S.k3.z] = 1;
    pres[(S.c3.w << 4) + S.k3.w] = 1;
    if (S.gp >= 0) pres[S.gp] = 1;
    if (S.gt >= 0) pres[S.gt] = 1;
    bar_lds();                                   // scatter visible

    // round-based readback: round r covers ids [2048r, 2048r+2048);
    // thread tid owns ids [2048r + 16*tid, +16) -> lex order == id order.
    const unsigned M = 0x01010101u;
    int base_cnt = 0;
#pragma unroll 1
    for (int r = 0; r < 2; r++) {
        const uint4 w = ((const uint4*)pres)[tid + (r << 7)];
        const int cnt = __popc(w.x & M) + __popc(w.y & M)
                      + __popc(w.z & M) + __popc(w.w & M);
        int pre = cnt;
#pragma unroll
        for (int d = 1; d < 64; d <<= 1) {
            const int v = __shfl_up(pre, d, 64);
            if (lane >= d) pre += v;
        }
        if (lane == 63) wsum[wv] = pre;
        bar_lds();
        const int w0 = wsum[0], w1 = wsum[1];
        int p = base_cnt + (wv ? w0 : 0) + pre - cnt;     // exclusive prefix
        if (p < 64) {
            const unsigned wrd[4] = {w.x, w.y, w.z, w.w};
            const int idbase = (r << 11) + (tid << 4);
#pragma unroll
            for (int c = 0; c < 4; c++) {
#pragma unroll
                for (int k = 0; k < 4; k++) {
                    if ((wrd[c] >> (8 * k)) & 1) {
                        if (p < 64) bagl[p] = idbase + 4 * c + k;
                        p++;
                    }
                }
            }
        }
        base_cnt += w0 + w1;                 // block-uniform running total
        if (base_cnt >= 64) break;           // bag full -> skip round 1
        bar_lds();                           // rare path: protect wsum reuse
    }
    bar_lds();                               // bagl ready

    if (tid < 64) out_bag[(size_t)b * 64 + tid] = (float)bagl[tid];

    // gather embedding rows: 320 float4 over 128 threads, coalesced writes
    const float4* tab4 = (const float4*)emb_table;
    float4* dst4 = (float4*)(out_emb + (size_t)b * (MAXLEN * EMB));
#pragma unroll
    for (int m = 0; m < 3; m++) {
        const int q = tid + (m << 7);
        if (q < MAXLEN * 5) {
            const int t = q / 5;
            const int mm = q - t * 5;
            const int row = bagl[t];
            dst4[q] = tab4[row * 5 + mm];
        }
    }
}

// ---------------- Kernel 1: 4-sample blocks, dbuf prefetch, lgkm-only barriers -
__global__ __launch_bounds__(128, 3) void bag_emb_kernel(
    const int* __restrict__ chars, const int* __restrict__ colors,
    const float* __restrict__ emb_table, const float* __restrict__ W_ih,
    float* __restrict__ out_emb, float* __restrict__ out_bag,
    float* __restrict__ proj, int nbag, int Btot)
{
    const int tid = threadIdx.x;

    if ((int)blockIdx.x >= nbag) {
        // ---- proj tail blocks: proj[g][j] = emb_table[g] . W_ih[j] ----
        const int gid = ((int)blockIdx.x - nbag) * 128 + tid;
        const int NP = (PADID + 1) * HID;          // 131104
        for (int idx = gid; idx < NP; idx += PROJ_BLOCKS * 128) {
            const int g = idx >> 5, j = idx & 31;
            const float* er = emb_table + (size_t)g * EMB;
            const float* wr = W_ih + j * EMB;
            float s = 0.f;
#pragma unroll
            for (int k = 0; k < EMB; k++) s += wr[k] * er[k];
            proj[idx] = s;
        }
        return;
    }

    __shared__ __align__(16) unsigned char pres[4096];
    __shared__ int bagl[64];
    __shared__ int wsum[2];

    const int lane = tid & 63;
    const int wv   = tid >> 6;
    const int sb   = (int)blockIdx.x * SPB;
    // clamp (redundant recompute, correct output) for non-multiple B
    const int s0 = min(sb + 0, Btot - 1);
    const int s1 = min(sb + 1, Btot - 1);
    const int s2 = min(sb + 2, Btot - 1);
    const int s3 = min(sb + 3, Btot - 1);

    Samp A, B;
    prefetch(A, chars, colors, s0, tid);
    prefetch(B, chars, colors, s1, tid);

    process(A, pres, bagl, wsum, s0, tid, lane, wv, emb_table, out_emb, out_bag);
    prefetch(A, chars, colors, s2, tid);
    process(B, pres, bagl, wsum, s1, tid, lane, wv, emb_table, out_emb, out_bag);
    prefetch(B, chars, colors, s3, tid);
    process(A, pres, bagl, wsum, s2, tid, lane, wv, emb_table, out_emb, out_bag);
    process(B, pres, bagl, wsum, s3, tid, lane, wv, emb_table, out_emb, out_bag);
}

// ------ Kernel 2: packed RNN, DPP all-gather, CHUNKED pv preload (16-deep) -----
__global__ __launch_bounds__(128)
__attribute__((amdgpu_waves_per_eu(2, 2)))
void rnn_kernel(
    const float* __restrict__ proj, const float* __restrict__ bagf,
    const float* __restrict__ W_hh,
    const float* __restrict__ b_ih, const float* __restrict__ b_hh,
    float* __restrict__ out_h)
{
    const int tid  = threadIdx.x;
    const int wv   = tid >> 6;
    const int lane = tid & 63;
    const int sl   = lane >> 4;        // sample slot within wave 0..3
    const int ib   = wv * 4 + sl;      // sample slot within block 0..7
    const int jj   = lane & 15;        // owns hidden units 2jj, 2jj+1
    const int b    = blockIdx.x * 8 + ib;

    // gather-position -> pair-xor map (butterfly: xor1, xor2, xor7, xor15)
    const int GMAP[16] = {0,1,2,3, 7,6,5,4, 15,14,13,12,11,10,9,8};

    // weights: w0[m]/w1[m] = rows (2jj, 2jj+1), column pair c = jj ^ GMAP[m]
    v2f w0[16], w1[16];
    const float2* wr0 = (const float2*)(W_hh + (2 * jj) * HID);
    const float2* wr1 = (const float2*)(W_hh + (2 * jj + 1) * HID);
#pragma unroll
    for (int m = 0; m < 16; m++) {
        const int c = jj ^ GMAP[m];
        float2 a = wr0[c], bb = wr1[c];
        w0[m] = (v2f){a.x, a.y};
        w1[m] = (v2f){bb.x, bb.y};
    }
    const float sb0 = b_ih[2 * jj]     + b_hh[2 * jj];
    const float sb1 = b_ih[2 * jj + 1] + b_hh[2 * jj + 1];

    const float* bps = bagf + (size_t)b * 64;
    const float2* proj2 = (const float2*)proj;   // row g -> proj2[g*16 + jj]

    float h0 = 0.f, h1 = 0.f;

#pragma unroll
    for (int ch = 0; ch < 4; ch++) {
        // ---- preload this chunk's 16 idx + pv (independent loads, MLP) ----
        int idx[16];
#pragma unroll
        for (int i = 0; i < 16; i++) idx[i] = (int)bps[ch * 16 + i];
        float2 pv[16];
#pragma unroll
        for (int i = 0; i < 16; i++) pv[i] = proj2[idx[i] * 16 + jj];

#pragma unroll
        for (int i = 0; i < 16; i++) {
            // sorted bag: (t < len) <=> bag[t] != PAD
            const bool upd = idx[i] < PADID;

            // ---- DPP butterfly all-gather: g[m] = pair (jj ^ GMAP[m]) ----
            v2f g[16];
            g[0] = (v2f){h0, h1};
            g[1] = (v2f){dppf<DPP_XOR1>(g[0].x), dppf<DPP_XOR1>(g[0].y)};
            g[2] = (v2f){dppf<DPP_XOR2>(g[0].x), dppf<DPP_XOR2>(g[0].y)};
            g[3] = (v2f){dppf<DPP_XOR2>(g[1].x), dppf<DPP_XOR2>(g[1].y)};
#pragma unroll
            for (int m = 0; m < 4; m++)
                g[4 + m] = (v2f){dppf<DPP_XOR7>(g[m].x), dppf<DPP_XOR7>(g[m].y)};
#pragma unroll
            for (int m = 0; m < 8; m++)
                g[8 + m] = (v2f){dppf<DPP_XORF>(g[m].x), dppf<DPP_XORF>(g[m].y)};

            // ---- 32 pk_fma: rows 2jj and 2jj+1 ----
            v2f a0 = (v2f){0.f, 0.f}, b0 = a0, a1 = a0, b1 = a0;
#pragma unroll
            for (int m = 0; m < 16; m += 2) {
                a0 = __builtin_elementwise_fma(w0[m],     g[m],     a0);
                b0 = __builtin_elementwise_fma(w0[m + 1], g[m + 1], b0);
                a1 = __builtin_elementwise_fma(w1[m],     g[m],     a1);
                b1 = __builtin_elementwise_fma(w1[m + 1], g[m + 1], b1);
            }
            float s0 = sb0 + pv[i].x + (a0.x + a0.y) + (b0.x + b0.y);
            float s1 = sb1 + pv[i].y + (a1.x + a1.y) + (b1.x + b1.y);

            // tanh(s) = 1 - 2/(e^{2s}+1); robust at both extremes, no clamp
            float e0 = __expf(2.f * s0);
            float e1 = __expf(2.f * s1);
            float th0 = 1.f - 2.f * __builtin_amdgcn_rcpf(e0 + 1.f);
            float th1 = 1.f - 2.f * __builtin_amdgcn_rcpf(e1 + 1.f);

            h0 = upd ? th0 : h0;
            h1 = upd ? th1 : h1;
        }
    }

    ((float2*)(out_h + (size_t)b * HID))[jj] = make_float2(h0, h1);
}

// ---------------- Fallback RNN (R4 exact) if ws can't hold proj ----------------
__global__ __launch_bounds__(128, 4) void rnn_kernel_noproj(
    const float* __restrict__ emb, const float* __restrict__ bagf,
    const float* __restrict__ W_ih, const float* __restrict__ W_hh,
    const float* __restrict__ b_ih, const float* __restrict__ b_hh,
    float* __restrict__ out_h)
{
    __shared__ float hbuf[4][32];
    const int tid = threadIdx.x;
    const int ib  = tid >> 5;
    const int j   = tid & 31;
    const int b   = blockIdx.x * 4 + ib;

    float wih[EMB];
#pragma unroll
    for (int k = 0; k < EMB; k++) wih[k] = W_ih[j * EMB + k];
    float whh[HID];
#pragma unroll
    for (int k = 0; k < HID; k++) whh[k] = W_hh[j * HID + k];
    const float sbias = b_ih[j] + b_hh[j];

    const float* bp = bagf + (size_t)b * 64;
    unsigned long long m0 = __ballot(bp[j]      < 4095.5f);
    unsigned long long m1 = __ballot(bp[32 + j] < 4095.5f);
    const int half = ib & 1;
    const int len = __popc((unsigned)(m0 >> (half * 32)))
                  + __popc((unsigned)(m1 >> (half * 32)));

    hbuf[ib][j] = 0.f;
    asm volatile("s_waitcnt lgkmcnt(0)" ::: "memory");

    float h = 0.f;
    const float* xb = emb + (size_t)b * (MAXLEN * EMB);
    for (int t = 0; t < MAXLEN; t++) {
        const float4* xp = (const float4*)(xb + t * EMB);
        float4 x0 = xp[0], x1 = xp[1], x2 = xp[2], x3 = xp[3], x4 = xp[4];
        float s = sbias;
        const float4* hb4 = (const float4*)hbuf[ib];
#pragma unroll
        for (int m = 0; m < 8; m++) {
            float4 hv = hb4[m];
            s += whh[4*m+0]*hv.x + whh[4*m+1]*hv.y
               + whh[4*m+2]*hv.z + whh[4*m+3]*hv.w;
        }
        s += wih[0]*x0.x + wih[1]*x0.y + wih[2]*x0.z + wih[3]*x0.w;
        s += wih[4]*x1.x + wih[5]*x1.y + wih[6]*x1.z + wih[7]*x1.w;
        s += wih[8]*x2.x + wih[9]*x2.y + wih[10]*x2.z + wih[11]*x2.w;
        s += wih[12]*x3.x + wih[13]*x3.y + wih[14]*x3.z + wih[15]*x3.w;
        s += wih[16]*x4.x + wih[17]*x4.y + wih[18]*x4.z + wih[19]*x4.w;
        s = fminf(fmaxf(s, -9.f), 9.f);
        float e = __expf(2.f * s);
        float th = (e - 1.f) * __builtin_amdgcn_rcpf(e + 1.f);
        h = (t < len) ? th : h;
        hbuf[ib][j] = h;
        asm volatile("s_waitcnt lgkmcnt(0)" ::: "memory");
    }
    out_h[(size_t)b * HID + j] = h;
}

extern "C" void kernel_launch(void* const* d_in, const int* in_sizes, int n_in,
                              void* d_out, int out_size, void* d_ws, size_t ws_size,
                              hipStream_t stream) {
    const int*   chars     = (const int*)d_in[0];
    const int*   colors    = (const int*)d_in[1];
    const float* emb_table = (const float*)d_in[2];
    const float* W_ih      = (const float*)d_in[3];
    const float* W_hh      = (const float*)d_in[4];
    const float* b_ih      = (const float*)d_in[5];
    const float* b_hh      = (const float*)d_in[6];

    const int B = in_sizes[0] / HW;      // 8192
    const int NBAG = (B + SPB - 1) / SPB;

    float* out     = (float*)d_out;
    float* out_h   = out;                                    // [B, 32]
    float* out_emb = out + (size_t)B * HID;                  // [B, 64, 20]
    float* out_bag = out_emb + (size_t)B * MAXLEN * EMB;     // [B, 64]

    const size_t proj_bytes = (size_t)(PADID + 1) * HID * sizeof(float);

    if (ws_size >= proj_bytes && (B % 8) == 0) {   // ws_size fixed -> same path every call
        float* proj = (float*)d_ws;
        bag_emb_kernel<<<NBAG + PROJ_BLOCKS, 128, 0, stream>>>(
            chars, colors, emb_table, W_ih, out_emb, out_bag, proj, NBAG, B);
        rnn_kernel<<<B / 8, 128, 0, stream>>>(proj, out_bag, W_hh, b_ih, b_hh, out_h);
    } else {
        bag_emb_kernel<<<NBAG, 128, 0, stream>>>(
            chars, colors, emb_table, W_ih, out_emb, out_bag, (float*)d_ws, NBAG, B);
        rnn_kernel_noproj<<<B / 4, 128, 0, stream>>>(out_emb, out_bag, W_ih, W_hh,
                                                     b_ih, b_hh, out_h);
    }
}

// Round 4
// 183.411 us; speedup vs baseline: 1.0140x; 1.0140x over previous
//
#include <hip/hip_runtime.h>

#define HW 1659      // 21*79
#define PADID 4096
#define EMB 20
#define HID 32
#define MAXLEN 64
#define PROJ_BLOCKS 128

typedef float v2f __attribute__((ext_vector_type(2)));
typedef float v4f __attribute__((ext_vector_type(4)));

// DPP lane-permute helper (pure VALU, no LDS pipe). CTRL is an immediate.
template <int CTRL>
__device__ __forceinline__ float dppf(float v) {
    return __builtin_bit_cast(float,
        __builtin_amdgcn_update_dpp(0, __builtin_bit_cast(int, v),
                                    CTRL, 0xF, 0xF, true));
}
#define DPP_XOR1 0xB1   // quad_perm [1,0,3,2]
#define DPP_XOR2 0x4E   // quad_perm [2,3,0,1]
#define DPP_XOR7 0x141  // row_half_mirror (xor 7 within 16)
#define DPP_XORF 0x140  // row_mirror      (xor 15 within 16)

// ---------------- Kernel 1: 128-thread block-per-sample bag+emb (R2, 46us) ----
__global__ __launch_bounds__(128, 4) void bag_emb_kernel(
    const int* __restrict__ chars, const int* __restrict__ colors,
    const float* __restrict__ emb_table, const float* __restrict__ W_ih,
    float* __restrict__ out_emb, float* __restrict__ out_bag,
    float* __restrict__ proj, int nbag)
{
    const int tid = threadIdx.x;

    if ((int)blockIdx.x >= nbag) {
        // ---- proj tail blocks: proj[g][j] = emb_table[g] . W_ih[j] ----
        const int gid = ((int)blockIdx.x - nbag) * 128 + tid;
        const int NP = (PADID + 1) * HID;          // 131104
        for (int idx = gid; idx < NP; idx += PROJ_BLOCKS * 128) {
            const int g = idx >> 5, j = idx & 31;
            const float* er = emb_table + (size_t)g * EMB;
            const float* wr = W_ih + j * EMB;
            float s = 0.f;
#pragma unroll
            for (int k = 0; k < EMB; k++) s += wr[k] * er[k];
            proj[idx] = s;
        }
        return;
    }

    __shared__ __align__(16) unsigned char pres[4096];
    __shared__ int bagl[64];
    __shared__ int wsum[2];

    const int lane = tid & 63;
    const int wv   = tid >> 6;
    const int b    = blockIdx.x;

    const int base = b * HW;
    const int pe = (4 - (base & 3)) & 3;          // peel to 16B alignment
    const int nv = (HW - pe) >> 2;                // always 414 int4 groups
    const int nt = HW - pe - (nv << 2);           // tail 0..3
    const int4* c4 = (const int4*)(chars + base + pe);
    const int4* k4 = (const int4*)(colors + base + pe);

    // ---- hoist ALL loads up front (8 int4 = 32 VGPRs, independent) ----
    int4 ca0 = c4[tid],       ka0 = k4[tid];
    int4 ca1 = c4[tid + 128], ka1 = k4[tid + 128];
    int4 ca2 = c4[tid + 256], ka2 = k4[tid + 256];     // 383 < 414 always
    const bool has3 = (tid + 384) < nv;                // tid < 30
    const int i3 = has3 ? tid + 384 : tid;
    int4 ca3 = c4[i3], ka3 = k4[i3];
    int gp = -1, gt = -1;
    if (tid < pe) gp = (chars[base + tid] << 4) + colors[base + tid];
    if (tid < nt) {
        const int i = base + pe + (nv << 2) + tid;
        gt = (chars[i] << 4) + colors[i];
    }

    // zero presence map: 256 uint4 over 128 threads
    ((uint4*)pres)[tid]       = make_uint4(0u, 0u, 0u, 0u);
    ((uint4*)pres)[tid + 128] = make_uint4(0u, 0u, 0u, 0u);
    if (tid < 64) bagl[tid] = PADID;
    __syncthreads();

    pres[(ca0.x << 4) + ka0.x] = 1;
    pres[(ca0.y << 4) + ka0.y] = 1;
    pres[(ca0.z << 4) + ka0.z] = 1;
    pres[(ca0.w << 4) + ka0.w] = 1;
    pres[(ca1.x << 4) + ka1.x] = 1;
    pres[(ca1.y << 4) + ka1.y] = 1;
    pres[(ca1.z << 4) + ka1.z] = 1;
    pres[(ca1.w << 4) + ka1.w] = 1;
    pres[(ca2.x << 4) + ka2.x] = 1;
    pres[(ca2.y << 4) + ka2.y] = 1;
    pres[(ca2.z << 4) + ka2.z] = 1;
    pres[(ca2.w << 4) + ka2.w] = 1;
    if (has3) {
        pres[(ca3.x << 4) + ka3.x] = 1;
        pres[(ca3.y << 4) + ka3.y] = 1;
        pres[(ca3.z << 4) + ka3.z] = 1;
        pres[(ca3.w << 4) + ka3.w] = 1;
    }
    if (gp >= 0) pres[gp] = 1;
    if (gt >= 0) pres[gt] = 1;
    __syncthreads();

    // ---- round-based readback: round r covers ids [2048r, 2048r+2048) ----
    const unsigned M = 0x01010101u;
    int base_cnt = 0;
#pragma unroll 1
    for (int r = 0; r < 2; r++) {
        const uint4 w = ((const uint4*)pres)[tid + (r << 7)];
        const int cnt = __popc(w.x & M) + __popc(w.y & M)
                      + __popc(w.z & M) + __popc(w.w & M);
        int pre = cnt;
#pragma unroll
        for (int d = 1; d < 64; d <<= 1) {
            const int v = __shfl_up(pre, d, 64);
            if (lane >= d) pre += v;
        }
        if (lane == 63) wsum[wv] = pre;
        __syncthreads();
        const int w0 = wsum[0], w1 = wsum[1];
        int p = base_cnt + (wv ? w0 : 0) + pre - cnt;     // exclusive prefix
        if (p < 64) {
            const unsigned wrd[4] = {w.x, w.y, w.z, w.w};
            const int idbase = (r << 11) + (tid << 4);
#pragma unroll
            for (int c = 0; c < 4; c++) {
#pragma unroll
                for (int k = 0; k < 4; k++) {
                    if ((wrd[c] >> (8 * k)) & 1) {
                        if (p < 64) bagl[p] = idbase + 4 * c + k;
                        p++;
                    }
                }
            }
        }
        base_cnt += w0 + w1;                 // block-uniform running total
        if (base_cnt >= 64) break;           // bag full -> skip round 1
        __syncthreads();                     // rare path: protect wsum reuse
    }
    __syncthreads();                         // bagl ready

    if (tid < 64) out_bag[(size_t)b * 64 + tid] = (float)bagl[tid];

    // gather embedding rows: 320 float4 over 128 threads, coalesced writes
    const float4* tab4 = (const float4*)emb_table;
    float4* dst4 = (float4*)(out_emb + (size_t)b * (MAXLEN * EMB));
#pragma unroll
    for (int m = 0; m < 3; m++) {
        const int q = tid + (m << 7);
        if (q < MAXLEN * 5) {
            const int t = q / 5;
            const int mm = q - t * 5;
            const int row = bagl[t];
            dst4[q] = tab4[row * 5 + mm];
        }
    }
}

// ------------------------- Kernel 2: packed RNN ------------------------------
// R3 postmortem: VGPR_Count=88 < static live set (~144+) proved the compiler
// was RE-LOADING W_hh weights (and pv) inside the 64-step loop under the
// waves_per_eu(2,2) cap -> ~100cy load latency on the critical chain per step
// -> 104us at VALUBusy 20%. Occupancy is grid-capped at 2 waves/SIMD anyway
// (8192 samples / 4 per wave = 2048 waves = 8/CU), so VGPRs up to 256 are
// FREE. Fix: launch_bounds(128,2) [cap 256], asm-pin weights + bag ids
// (opaque origin -> cannot rematerialize), pv gathers double-buffered one
// 8-step chunk ahead with sched_barrier(0) fences (single BB -> no sinking).

__device__ __forceinline__ void pv_fetch8(
    const float (&idxf)[64], int c0,
    const v2f* __restrict__ proj2, int jj, v2f (&pv)[8])
{
#pragma unroll
    for (int i = 0; i < 8; i++) {
        const int row = (int)idxf[c0 + i];      // ids 0..4096, exact in f32
        pv[i] = proj2[row * 16 + jj];
    }
}

__device__ __forceinline__ void rnn_chunk8(
    const float (&idxf)[64], int c0, const v2f (&pv)[8],
    const v2f (&w0)[16], const v2f (&w1)[16],
    float sb0, float sb1, float& h0, float& h1)
{
#pragma unroll
    for (int i = 0; i < 8; i++) {
        // sorted bag: (t < len) <=> bag[t] != PAD
        const bool upd = idxf[c0 + i] < 4095.5f;

        // ---- DPP butterfly all-gather: g[m] = pair (jj ^ GMAP[m]) ----
        v2f g[16];
        g[0] = (v2f){h0, h1};
        g[1] = (v2f){dppf<DPP_XOR1>(g[0][0]), dppf<DPP_XOR1>(g[0][1])};
        g[2] = (v2f){dppf<DPP_XOR2>(g[0][0]), dppf<DPP_XOR2>(g[0][1])};
        g[3] = (v2f){dppf<DPP_XOR2>(g[1][0]), dppf<DPP_XOR2>(g[1][1])};
#pragma unroll
        for (int m = 0; m < 4; m++)
            g[4 + m] = (v2f){dppf<DPP_XOR7>(g[m][0]), dppf<DPP_XOR7>(g[m][1])};
#pragma unroll
        for (int m = 0; m < 8; m++)
            g[8 + m] = (v2f){dppf<DPP_XORF>(g[m][0]), dppf<DPP_XORF>(g[m][1])};

        // ---- 32 pk_fma: rows 2jj and 2jj+1 ----
        v2f a0 = (v2f){0.f, 0.f}, b0 = a0, a1 = a0, b1 = a0;
#pragma unroll
        for (int m = 0; m < 16; m += 2) {
            a0 = __builtin_elementwise_fma(w0[m],     g[m],     a0);
            b0 = __builtin_elementwise_fma(w0[m + 1], g[m + 1], b0);
            a1 = __builtin_elementwise_fma(w1[m],     g[m],     a1);
            b1 = __builtin_elementwise_fma(w1[m + 1], g[m + 1], b1);
        }
        float s0 = sb0 + pv[i][0] + (a0[0] + a0[1]) + (b0[0] + b0[1]);
        float s1 = sb1 + pv[i][1] + (a1[0] + a1[1]) + (b1[0] + b1[1]);

        // tanh(s) = 1 - 2/(e^{2s}+1); robust at both extremes, no clamp
        float e0 = __expf(2.f * s0);
        float e1 = __expf(2.f * s1);
        float th0 = 1.f - 2.f * __builtin_amdgcn_rcpf(e0 + 1.f);
        float th1 = 1.f - 2.f * __builtin_amdgcn_rcpf(e1 + 1.f);

        h0 = upd ? th0 : h0;
        h1 = upd ? th1 : h1;
    }
}

__global__ __launch_bounds__(128, 2)
void rnn_kernel(
    const float* __restrict__ proj, const float* __restrict__ bagf,
    const float* __restrict__ W_hh,
    const float* __restrict__ b_ih, const float* __restrict__ b_hh,
    float* __restrict__ out_h)
{
    const int tid  = threadIdx.x;
    const int wv   = tid >> 6;
    const int lane = tid & 63;
    const int sl   = lane >> 4;        // sample slot within wave 0..3
    const int ib   = wv * 4 + sl;      // sample slot within block 0..7
    const int jj   = lane & 15;        // owns hidden units 2jj, 2jj+1
    const int b    = blockIdx.x * 8 + ib;

    // gather-position -> pair-xor map (butterfly: xor1, xor2, xor7, xor15)
    const int GMAP[16] = {0,1,2,3, 7,6,5,4, 15,14,13,12,11,10,9,8};

    // weights: w0[m]/w1[m] = rows (2jj, 2jj+1), column pair c = jj ^ GMAP[m]
    v2f w0[16], w1[16];
    const v2f* wr0 = (const v2f*)(W_hh + (2 * jj) * HID);
    const v2f* wr1 = (const v2f*)(W_hh + (2 * jj + 1) * HID);
#pragma unroll
    for (int m = 0; m < 16; m++) {
        const int c = jj ^ GMAP[m];
        w0[m] = wr0[c];
        w1[m] = wr1[c];
    }
    // Pin weights in VGPRs: opaque origin -> cannot be rematerialized/sunk.
#pragma unroll
    for (int m = 0; m < 16; m++) {
        asm volatile("" : "+v"(w0[m]));
        asm volatile("" : "+v"(w1[m]));
    }

    const float sb0 = b_ih[2 * jj]     + b_hh[2 * jj];
    const float sb1 = b_ih[2 * jj + 1] + b_hh[2 * jj + 1];

    const v2f* proj2 = (const v2f*)proj;        // row g -> proj2[g*16 + jj]

    // ---- all 64 bag ids resident (16 x b128 loads, issued together) ----
    v4f q[16];
    const v4f* bp4 = (const v4f*)(bagf + (size_t)b * 64);
#pragma unroll
    for (int t = 0; t < 16; t++) q[t] = bp4[t];
#pragma unroll
    for (int t = 0; t < 16; t++) asm volatile("" : "+v"(q[t]));  // pin
    float idxf[64];
#pragma unroll
    for (int t = 0; t < 16; t++) {
        idxf[4 * t + 0] = q[t][0];
        idxf[4 * t + 1] = q[t][1];
        idxf[4 * t + 2] = q[t][2];
        idxf[4 * t + 3] = q[t][3];
    }

    float h0 = 0.f, h1 = 0.f;
    v2f pvA[8], pvB[8];

    // software pipeline: pv(k+1) issued before chunk(k); counted vmcnt keeps
    // the newer 8 loads in flight while chunk(k) computes (~1200cy cover).
    pv_fetch8(idxf, 0,  proj2, jj, pvA);
    pv_fetch8(idxf, 8,  proj2, jj, pvB);
    __builtin_amdgcn_sched_barrier(0);
    rnn_chunk8(idxf, 0,  pvA, w0, w1, sb0, sb1, h0, h1);
    pv_fetch8(idxf, 16, proj2, jj, pvA);
    __builtin_amdgcn_sched_barrier(0);
    rnn_chunk8(idxf, 8,  pvB, w0, w1, sb0, sb1, h0, h1);
    pv_fetch8(idxf, 24, proj2, jj, pvB);
    __builtin_amdgcn_sched_barrier(0);
    rnn_chunk8(idxf, 16, pvA, w0, w1, sb0, sb1, h0, h1);
    pv_fetch8(idxf, 32, proj2, jj, pvA);
    __builtin_amdgcn_sched_barrier(0);
    rnn_chunk8(idxf, 24, pvB, w0, w1, sb0, sb1, h0, h1);
    pv_fetch8(idxf, 40, proj2, jj, pvB);
    __builtin_amdgcn_sched_barrier(0);
    rnn_chunk8(idxf, 32, pvA, w0, w1, sb0, sb1, h0, h1);
    pv_fetch8(idxf, 48, proj2, jj, pvA);
    __builtin_amdgcn_sched_barrier(0);
    rnn_chunk8(idxf, 40, pvB, w0, w1, sb0, sb1, h0, h1);
    pv_fetch8(idxf, 56, proj2, jj, pvB);
    __builtin_amdgcn_sched_barrier(0);
    rnn_chunk8(idxf, 48, pvA, w0, w1, sb0, sb1, h0, h1);
    rnn_chunk8(idxf, 56, pvB, w0, w1, sb0, sb1, h0, h1);

    ((float2*)(out_h + (size_t)b * HID))[jj] = make_float2(h0, h1);
}

// ---------------- Fallback RNN (R4 exact) if ws can't hold proj ----------------
__global__ __launch_bounds__(128, 4) void rnn_kernel_noproj(
    const float* __restrict__ emb, const float* __restrict__ bagf,
    const float* __restrict__ W_ih, const float* __restrict__ W_hh,
    const float* __restrict__ b_ih, const float* __restrict__ b_hh,
    float* __restrict__ out_h)
{
    __shared__ float hbuf[4][32];
    const int tid = threadIdx.x;
    const int ib  = tid >> 5;
    const int j   = tid & 31;
    const int b   = blockIdx.x * 4 + ib;

    float wih[EMB];
#pragma unroll
    for (int k = 0; k < EMB; k++) wih[k] = W_ih[j * EMB + k];
    float whh[HID];
#pragma unroll
    for (int k = 0; k < HID; k++) whh[k] = W_hh[j * HID + k];
    const float sbias = b_ih[j] + b_hh[j];

    const float* bp = bagf + (size_t)b * 64;
    unsigned long long m0 = __ballot(bp[j]      < 4095.5f);
    unsigned long long m1 = __ballot(bp[32 + j] < 4095.5f);
    const int half = ib & 1;
    const int len = __popc((unsigned)(m0 >> (half * 32)))
                  + __popc((unsigned)(m1 >> (half * 32)));

    hbuf[ib][j] = 0.f;
    asm volatile("s_waitcnt lgkmcnt(0)" ::: "memory");

    float h = 0.f;
    const float* xb = emb + (size_t)b * (MAXLEN * EMB);
    for (int t = 0; t < MAXLEN; t++) {
        const float4* xp = (const float4*)(xb + t * EMB);
        float4 x0 = xp[0], x1 = xp[1], x2 = xp[2], x3 = xp[3], x4 = xp[4];
        float s = sbias;
        const float4* hb4 = (const float4*)hbuf[ib];
#pragma unroll
        for (int m = 0; m < 8; m++) {
            float4 hv = hb4[m];
            s += whh[4*m+0]*hv.x + whh[4*m+1]*hv.y
               + whh[4*m+2]*hv.z + whh[4*m+3]*hv.w;
        }
        s += wih[0]*x0.x + wih[1]*x0.y + wih[2]*x0.z + wih[3]*x0.w;
        s += wih[4]*x1.x + wih[5]*x1.y + wih[6]*x1.z + wih[7]*x1.w;
        s += wih[8]*x2.x + wih[9]*x2.y + wih[10]*x2.z + wih[11]*x2.w;
        s += wih[12]*x3.x + wih[13]*x3.y + wih[14]*x3.z + wih[15]*x3.w;
        s += wih[16]*x4.x + wih[17]*x4.y + wih[18]*x4.z + wih[19]*x4.w;
        s = fminf(fmaxf(s, -9.f), 9.f);
        float e = __expf(2.f * s);
        float th = (e - 1.f) * __builtin_amdgcn_rcpf(e + 1.f);
        h = (t < len) ? th : h;
        hbuf[ib][j] = h;
        asm volatile("s_waitcnt lgkmcnt(0)" ::: "memory");
    }
    out_h[(size_t)b * HID + j] = h;
}

extern "C" void kernel_launch(void* const* d_in, const int* in_sizes, int n_in,
                              void* d_out, int out_size, void* d_ws, size_t ws_size,
                              hipStream_t stream) {
    const int*   chars     = (const int*)d_in[0];
    const int*   colors    = (const int*)d_in[1];
    const float* emb_table = (const float*)d_in[2];
    const float* W_ih      = (const float*)d_in[3];
    const float* W_hh      = (const float*)d_in[4];
    const float* b_ih      = (const float*)d_in[5];
    const float* b_hh      = (const float*)d_in[6];

    const int B = in_sizes[0] / HW;      // 8192

    float* out     = (float*)d_out;
    float* out_h   = out;                                    // [B, 32]
    float* out_emb = out + (size_t)B * HID;                  // [B, 64, 20]
    float* out_bag = out_emb + (size_t)B * MAXLEN * EMB;     // [B, 64]

    const size_t proj_bytes = (size_t)(PADID + 1) * HID * sizeof(float);

    if (ws_size >= proj_bytes && (B % 8) == 0) {   // ws_size fixed -> same path every call
        float* proj = (float*)d_ws;
        bag_emb_kernel<<<B + PROJ_BLOCKS, 128, 0, stream>>>(
            chars, colors, emb_table, W_ih, out_emb, out_bag, proj, B);
        rnn_kernel<<<B / 8, 128, 0, stream>>>(proj, out_bag, W_hh, b_ih, b_hh, out_h);
    } else {
        bag_emb_kernel<<<B, 128, 0, stream>>>(
            chars, colors, emb_table, W_ih, out_emb, out_bag, (float*)d_ws, B);
        rnn_kernel_noproj<<<B / 4, 128, 0, stream>>>(out_emb, out_bag, W_ih, W_hh,
                                                     b_ih, b_hh, out_h);
    }
}